// Round 5
// baseline (464.503 us; speedup 1.0000x reference)
//
#include <hip/hip_runtime.h>
#include <hip/hip_bf16.h>

#define HID 128
#define OUT_DIM 112
#define CAP 4096

typedef short bf16x8 __attribute__((ext_vector_type(8)));
typedef float f32x4 __attribute__((ext_vector_type(4)));

__device__ __forceinline__ ushort f2b(float f) {
  __hip_bfloat16 h = __float2bfloat16(f);  // RNE
  return *reinterpret_cast<ushort*>(&h);
}

// ---- fp32 -> bf16 bulk convert (4 elems/thread)
__global__ __launch_bounds__(256) void f2b_kernel(
    const float* __restrict__ in, ushort* __restrict__ out, int n4) {
  int i = blockIdx.x * 256 + threadIdx.x;
  if (i >= n4) return;
  float4 v = ((const float4*)in)[i];
  ushort4 r;
  r.x = f2b(v.x); r.y = f2b(v.y); r.z = f2b(v.z); r.w = f2b(v.w);
  ((ushort4*)out)[i] = r;
}

// ---- pack all 5 weight matrices into MFMA B-fragment order in ONE launch.
// wb[ks][nt][lane][j] = bf16( W[nt*16 + (lane&15)][ks*32 + (lane>>4)*8 + j] )
__global__ __launch_bounds__(256) void packw_all_kernel(
    const float* __restrict__ Wl1, const float* __restrict__ Wr1,
    const float* __restrict__ Wl2, const float* __restrict__ Wr2,
    const float* __restrict__ Wo, ushort* __restrict__ WB1,
    ushort* __restrict__ WB2, ushort* __restrict__ WBO) {
  int p = blockIdx.x * 256 + threadIdx.x;  // 0..79871
  const float* W;
  ushort* wb;
  int ntiles, off;
  if (p < 16384)      { W = Wl1; wb = WB1;         ntiles = 8; off = p; }
  else if (p < 32768) { W = Wr1; wb = WB1 + 16384; ntiles = 8; off = p - 16384; }
  else if (p < 49152) { W = Wl2; wb = WB2;         ntiles = 8; off = p - 32768; }
  else if (p < 65536) { W = Wr2; wb = WB2 + 16384; ntiles = 8; off = p - 49152; }
  else if (p < 79872) { W = Wo;  wb = WBO;         ntiles = 7; off = p - 65536; }
  else return;
  int j = off & 7;
  int l = (off >> 3) & 63;
  int rest = off >> 9;
  int nt = rest % ntiles;
  int ks = rest / ntiles;
  int nn = nt * 16 + (l & 15);
  int k = ks * 32 + (l >> 4) * 8 + j;
  wb[off] = f2b(W[nn * 128 + k]);
}

// ---- sort pass 0: per-block LDS histogram of dst>>7, merged to global
__global__ __launch_bounds__(256) void hist_kernel(
    const int* __restrict__ dst, int* __restrict__ gcount, int e, int nb) {
  __shared__ int lh[1024];
  const int t = threadIdx.x;
  for (int i = t; i < nb; i += 256) lh[i] = 0;
  __syncthreads();
  int base = blockIdx.x * 4096;
#pragma unroll
  for (int j = 0; j < 16; ++j) {
    int i = base + j * 256 + t;
    if (i < e) atomicAdd(&lh[dst[i] >> 7], 1);
  }
  __syncthreads();
  for (int i = t; i < nb; i += 256)
    if (lh[i]) atomicAdd(&gcount[i], lh[i]);
}

// ---- sort pass 1: scan bucket counts -> bases + cursors; rowstart[n]=e
__global__ __launch_bounds__(1024) void scan_nb_kernel(
    const int* __restrict__ gcount, int* __restrict__ gbase,
    int* __restrict__ gcursor, int* __restrict__ rowstart,
    int e, int n, int nb) {
  __shared__ int wsum[16];
  const int t = threadIdx.x, lane = t & 63, wid = t >> 6;
  int v = (t < nb) ? gcount[t] : 0;
  int s = v;
#pragma unroll
  for (int off = 1; off < 64; off <<= 1) {
    int u = __shfl_up(s, off, 64);
    if (lane >= off) s += u;
  }
  if (lane == 63) wsum[wid] = s;
  __syncthreads();
  if (wid == 0) {
    int ws = (lane < 16) ? wsum[lane] : 0;
#pragma unroll
    for (int off = 1; off < 16; off <<= 1) {
      int u = __shfl_up(ws, off, 64);
      if (lane >= off) ws += u;
    }
    if (lane < 16) wsum[lane] = ws;
  }
  __syncthreads();
  int excl = s - v + (wid ? wsum[wid - 1] : 0);
  if (t < nb) {
    gbase[t] = excl;
    gcursor[t] = excl;
  }
  if (t == 0) {
    gbase[nb] = e;
    rowstart[n] = e;
  }
}

// ---- sort pass 2: bucket edges; write packed (src<<7)|(dst&127)
__global__ __launch_bounds__(1024) void bucket_scatter_kernel(
    const int* __restrict__ src, const int* __restrict__ dst,
    int* __restrict__ gcursor, uint* __restrict__ bedges, int e, int nb) {
  __shared__ int lh[1024];
  __shared__ int lstart[1024];
  __shared__ int wsum[16];
  __shared__ uint sp[8192];
  __shared__ ushort sb[8192];
  const int t = threadIdx.x, lane = t & 63, wid = t >> 6;
  const int base = blockIdx.x * 8192;
  const int ecnt = min(8192, e - base);
  for (int i = t; i < nb; i += 1024) lh[i] = 0;
  __syncthreads();
  int myb[8], myr[8];
  uint myp[8];
#pragma unroll
  for (int j = 0; j < 8; ++j) {
    int i = base + j * 1024 + t;
    myb[j] = -1;
    if (i < e) {
      int d = dst[i];
      int sv = src[i];
      int b = d >> 7;
      myb[j] = b;
      myp[j] = ((uint)sv << 7) | (uint)(d & 127);
      myr[j] = atomicAdd(&lh[b], 1);
    }
  }
  __syncthreads();
  int cnt = (t < nb) ? lh[t] : 0;
  int s = cnt;
#pragma unroll
  for (int off = 1; off < 64; off <<= 1) {
    int u = __shfl_up(s, off, 64);
    if (lane >= off) s += u;
  }
  if (lane == 63) wsum[wid] = s;
  __syncthreads();
  if (wid == 0) {
    int ws = (lane < 16) ? wsum[lane] : 0;
#pragma unroll
    for (int off = 1; off < 16; off <<= 1) {
      int u = __shfl_up(ws, off, 64);
      if (lane >= off) ws += u;
    }
    if (lane < 16) wsum[lane] = ws;
  }
  __syncthreads();
  int excl = s - cnt + (wid ? wsum[wid - 1] : 0);
  if (t < nb) lstart[t] = excl;
  __syncthreads();
  if (t < nb) lh[t] = (cnt > 0) ? atomicAdd(&gcursor[t], cnt) : 0;
  __syncthreads();
#pragma unroll
  for (int j = 0; j < 8; ++j) {
    if (myb[j] >= 0) {
      int slot = lstart[myb[j]] + myr[j];
      sp[slot] = myp[j];
      sb[slot] = (ushort)myb[j];
    }
  }
  __syncthreads();
#pragma unroll
  for (int j = 0; j < 8; ++j) {
    int i = j * 1024 + t;
    if (i < ecnt) {
      int b = sb[i];
      int pos = lh[b] + (i - lstart[b]);
      bedges[pos] = sp[i];
    }
  }
}

// ---- sort pass 3: per-bucket counting sort by dst&127 -> csr_src, rowstart, dinv
__global__ __launch_bounds__(256) void csr_build_kernel(
    const uint* __restrict__ bedges, const int* __restrict__ gbase,
    int* __restrict__ rowstart, float* __restrict__ dinv,
    int* __restrict__ csr_src, int n) {
  __shared__ int lh[128];
  __shared__ int lst[128];
  __shared__ int lcur[128];
  __shared__ int wsum2[4];
  __shared__ int lsorted[CAP];
  const int t = threadIdx.x;
  const int bkt = blockIdx.x;
  const int node0 = bkt << 7;
  const int g0 = gbase[bkt], g1 = gbase[bkt + 1];
  const int cnt = g1 - g0;
  if (t < 128) lh[t] = 0;
  __syncthreads();
  for (int i = t; i < cnt; i += 256)
    atomicAdd(&lh[bedges[g0 + i] & 127], 1);
  __syncthreads();
  const int lane = t & 63, wid = t >> 6;
  int v = (t < 128) ? lh[t] : 0;
  int s = v;
#pragma unroll
  for (int off = 1; off < 64; off <<= 1) {
    int u = __shfl_up(s, off, 64);
    if (lane >= off) s += u;
  }
  if (t < 128 && lane == 63) wsum2[wid] = s;
  __syncthreads();
  int excl = s - v + ((wid == 1) ? wsum2[0] : 0);
  if (t < 128) {
    lst[t] = excl;
    lcur[t] = excl;
    int node = node0 + t;
    if (node < n) {
      rowstart[node] = g0 + excl;
      dinv[node] = 1.0f / (float)max(v, 1);
    }
  }
  __syncthreads();
  for (int i = t; i < cnt; i += 256) {
    uint p = bedges[g0 + i];
    int d = p & 127;
    int slot = atomicAdd(&lcur[d], 1);
    int sv = (int)(p >> 7);
    if (slot < CAP) lsorted[slot] = sv;
    else csr_src[g0 + slot] = sv;
  }
  __syncthreads();
  int lim = min(cnt, CAP);
  for (int i = t; i < lim; i += 256) csr_src[g0 + i] = lsorted[i];
}

// ---- gather-mean of 16 nodes per wave into LDS A-tile (row = local node)
__device__ __forceinline__ void gather_tile(
    const ushort* __restrict__ xb, const int* __restrict__ csr_src,
    const int* __restrict__ rowstart, const float* __restrict__ dinv,
    ushort* __restrict__ zA, int block0, int n, int wave, int lane) {
#pragma unroll 1
  for (int j = 0; j < 16; ++j) {
    int lrow = wave * 16 + j;
    int node = block0 + lrow;
    uint r = 0;
    if (node < n) {
      int s = rowstart[node], e1 = rowstart[node + 1];
      float ax = 0.f, ay = 0.f;
      int e = s;
      for (; e + 4 <= e1; e += 4) {
        int s0 = csr_src[e], s1 = csr_src[e + 1];
        int s2 = csr_src[e + 2], s3 = csr_src[e + 3];
        uint u0 = ((const uint*)(xb + (size_t)s0 * 128))[lane];
        uint u1 = ((const uint*)(xb + (size_t)s1 * 128))[lane];
        uint u2 = ((const uint*)(xb + (size_t)s2 * 128))[lane];
        uint u3 = ((const uint*)(xb + (size_t)s3 * 128))[lane];
        ax += (__uint_as_float(u0 << 16) + __uint_as_float(u1 << 16)) +
              (__uint_as_float(u2 << 16) + __uint_as_float(u3 << 16));
        ay += (__uint_as_float(u0 & 0xffff0000u) + __uint_as_float(u1 & 0xffff0000u)) +
              (__uint_as_float(u2 & 0xffff0000u) + __uint_as_float(u3 & 0xffff0000u));
      }
      for (; e < e1; ++e) {
        uint u = ((const uint*)(xb + (size_t)csr_src[e] * 128))[lane];
        ax += __uint_as_float(u << 16);
        ay += __uint_as_float(u & 0xffff0000u);
      }
      float sc = dinv[node];
      r = (uint)f2b(ax * sc) | ((uint)f2b(ay * sc) << 16);
    }
    ((uint*)(zA + lrow * 128))[lane] = r;
  }
}

// ---- fused layer 1: gather-mean + [mean|x] MFMA + relu -> h1 (bf16)
__global__ __launch_bounds__(256) void sage1_kernel(
    const ushort* __restrict__ xb, const int* __restrict__ csr_src,
    const int* __restrict__ rowstart, const float* __restrict__ dinv,
    const ushort* __restrict__ wb, const float* __restrict__ bias,
    ushort* __restrict__ outb, int n) {
  __shared__ ushort zA[64 * 128];
  __shared__ ushort zX[64 * 128];
  const int t = threadIdx.x;
  const int block0 = blockIdx.x * 64;
  const int lane = t & 63;
  const int wave = t >> 6;
  // stage x tile (coalesced)
#pragma unroll
  for (int i = 0; i < 4; ++i) {
    int c = i * 256 + t;
    int row = c >> 4;
    int col = c & 15;
    int node = block0 + row;
    int4 vx = make_int4(0, 0, 0, 0);
    if (node < n) vx = ((const int4*)(xb + (size_t)node * 128))[col];
    ((int4*)zX)[c] = vx;
  }
  // gather-mean into zA
  gather_tile(xb, csr_src, rowstart, dinv, zA, block0, n, wave, lane);
  __syncthreads();
  const int m0 = wave * 16;
  const int cidx = lane & 15;
  const int quad = lane >> 4;
  f32x4 acc[8];
#pragma unroll
  for (int nt = 0; nt < 8; ++nt) acc[nt] = (f32x4){0.f, 0.f, 0.f, 0.f};
#pragma unroll
  for (int s = 0; s < 2; ++s) {
    const ushort* zs = (s == 0) ? zA : zX;
#pragma unroll
    for (int ks = 0; ks < 4; ++ks) {
      bf16x8 a = *(const bf16x8*)(zs + (m0 + cidx) * 128 + ks * 32 + quad * 8);
      const ushort* wp = wb + ((size_t)((s * 4 + ks) * 8) * 64 + lane) * 8;
#pragma unroll
      for (int nt = 0; nt < 8; ++nt) {
        bf16x8 b = *(const bf16x8*)(wp + nt * 512);
        acc[nt] = __builtin_amdgcn_mfma_f32_16x16x32_bf16(a, b, acc[nt], 0, 0, 0);
      }
    }
  }
  __syncthreads();
#pragma unroll
  for (int nt = 0; nt < 8; ++nt) {
    float bv = bias[nt * 16 + cidx];
#pragma unroll
    for (int i = 0; i < 4; ++i) {
      float v = fmaxf(acc[nt][i] + bv, 0.f);
      zA[(m0 + quad * 4 + i) * 128 + nt * 16 + cidx] = f2b(v);
    }
  }
  __syncthreads();
#pragma unroll
  for (int i = 0; i < 4; ++i) {
    int c = i * 256 + t;
    int row = c >> 4;
    int col = c & 15;
    int node = block0 + row;
    if (node < n) ((int4*)(outb + (size_t)node * 128))[col] = ((const int4*)zA)[c];
  }
}

// ---- fused layer 2 + out: gather-mean(h1) + [mean|h1] MFMA + relu -> h2
// (LDS, per-wave-private rows) + out MFMA -> fp32 d_out [n x 112]
__global__ __launch_bounds__(256) void sage2_kernel(
    const ushort* __restrict__ hb, const int* __restrict__ csr_src,
    const int* __restrict__ rowstart, const float* __restrict__ dinv,
    const ushort* __restrict__ wb, const float* __restrict__ bias,
    const ushort* __restrict__ wbo, const float* __restrict__ bias_o,
    float* __restrict__ outp, int n) {
  __shared__ ushort zA[64 * 128];
  __shared__ ushort zX[64 * 128];
  const int t = threadIdx.x;
  const int block0 = blockIdx.x * 64;
  const int lane = t & 63;
  const int wave = t >> 6;
#pragma unroll
  for (int i = 0; i < 4; ++i) {
    int c = i * 256 + t;
    int row = c >> 4;
    int col = c & 15;
    int node = block0 + row;
    int4 vx = make_int4(0, 0, 0, 0);
    if (node < n) vx = ((const int4*)(hb + (size_t)node * 128))[col];
    ((int4*)zX)[c] = vx;
  }
  gather_tile(hb, csr_src, rowstart, dinv, zA, block0, n, wave, lane);
  __syncthreads();
  const int m0 = wave * 16;
  const int cidx = lane & 15;
  const int quad = lane >> 4;
  f32x4 acc[8];
#pragma unroll
  for (int nt = 0; nt < 8; ++nt) acc[nt] = (f32x4){0.f, 0.f, 0.f, 0.f};
#pragma unroll
  for (int s = 0; s < 2; ++s) {
    const ushort* zs = (s == 0) ? zA : zX;
#pragma unroll
    for (int ks = 0; ks < 4; ++ks) {
      bf16x8 a = *(const bf16x8*)(zs + (m0 + cidx) * 128 + ks * 32 + quad * 8);
      const ushort* wp = wb + ((size_t)((s * 4 + ks) * 8) * 64 + lane) * 8;
#pragma unroll
      for (int nt = 0; nt < 8; ++nt) {
        bf16x8 b = *(const bf16x8*)(wp + nt * 512);
        acc[nt] = __builtin_amdgcn_mfma_f32_16x16x32_bf16(a, b, acc[nt], 0, 0, 0);
      }
    }
  }
  // h2 = relu(acc+bias) -> bf16 into zX. Each wave touches only rows
  // [m0, m0+16) for both its A-reads above and D-writes here, and the
  // out-phase A-reads below are also rows [m0, m0+16): no cross-wave
  // hazard, no barrier needed (per-wave LDS ops are in-order).
#pragma unroll
  for (int nt = 0; nt < 8; ++nt) {
    float bv = bias[nt * 16 + cidx];
#pragma unroll
    for (int i = 0; i < 4; ++i) {
      float v = fmaxf(acc[nt][i] + bv, 0.f);
      zX[(m0 + quad * 4 + i) * 128 + nt * 16 + cidx] = f2b(v);
    }
  }
  // out projection: acc2 = h2 @ Wout^T
  f32x4 acc2[7];
#pragma unroll
  for (int nt = 0; nt < 7; ++nt) acc2[nt] = (f32x4){0.f, 0.f, 0.f, 0.f};
#pragma unroll
  for (int ks = 0; ks < 4; ++ks) {
    bf16x8 a = *(const bf16x8*)(zX + (m0 + cidx) * 128 + ks * 32 + quad * 8);
    const ushort* wp = wbo + ((size_t)(ks * 7) * 64 + lane) * 8;
#pragma unroll
    for (int nt = 0; nt < 7; ++nt) {
      bf16x8 b = *(const bf16x8*)(wp + nt * 512);
      acc2[nt] = __builtin_amdgcn_mfma_f32_16x16x32_bf16(a, b, acc2[nt], 0, 0, 0);
    }
  }
  // direct store: lanes of a wave cover 16 cols x 4 rows per (nt,i) pair
#pragma unroll
  for (int nt = 0; nt < 7; ++nt) {
    float bv = bias_o[nt * 16 + cidx];
#pragma unroll
    for (int i = 0; i < 4; ++i) {
      int node = block0 + m0 + quad * 4 + i;
      if (node < n)
        outp[(size_t)node * OUT_DIM + nt * 16 + cidx] = acc2[nt][i] + bv;
    }
  }
}

extern "C" void kernel_launch(void* const* d_in, const int* in_sizes, int n_in,
                              void* d_out, int out_size, void* d_ws, size_t ws_size,
                              hipStream_t stream) {
  const float* x     = (const float*)d_in[0];
  const int*   ei    = (const int*)d_in[1];
  const float* W_l1  = (const float*)d_in[2];
  const float* b_l1  = (const float*)d_in[3];
  const float* W_r1  = (const float*)d_in[4];
  const float* W_l2  = (const float*)d_in[5];
  const float* b_l2  = (const float*)d_in[6];
  const float* W_r2  = (const float*)d_in[7];
  const float* W_out = (const float*)d_in[8];
  const float* b_out = (const float*)d_in[9];

  const int N = in_sizes[0] / 128;
  const int E = in_sizes[1] / 2;
  const int NB = (N + 127) >> 7;
  const int* src = ei;
  const int* dst = ei + E;

  ushort* XB = (ushort*)d_ws;               // N*128 bf16 (x)
  ushort* HB = XB + (size_t)N * 128;        // N*128 bf16 (h1)
  float* DINV = (float*)(HB + (size_t)N * 128);  // N f32
  ushort* WB1 = (ushort*)(DINV + N);        // 32768
  ushort* WB2 = WB1 + 32768;                // 32768
  ushort* WBO = WB2 + 32768;                // 14336
  int* GCOUNT   = (int*)(WBO + 14336);      // NB
  int* GBASE    = GCOUNT + NB;              // NB+1
  int* GCURSOR  = GBASE + NB + 1;           // NB
  int* ROWSTART = GCURSOR + NB;             // N+1
  uint* BEDGES  = (uint*)(ROWSTART + N + 1);// E
  int* CSRSRC   = (int*)(BEDGES + E);       // E

  // ---- CSR build via two-pass counting sort
  hipMemsetAsync(GCOUNT, 0, (size_t)NB * sizeof(int), stream);
  hist_kernel<<<(E + 4095) / 4096, 256, 0, stream>>>(dst, GCOUNT, E, NB);
  scan_nb_kernel<<<1, 1024, 0, stream>>>(GCOUNT, GBASE, GCURSOR, ROWSTART, E, N, NB);
  bucket_scatter_kernel<<<(E + 8191) / 8192, 1024, 0, stream>>>(
      src, dst, GCURSOR, BEDGES, E, NB);
  csr_build_kernel<<<NB, 256, 0, stream>>>(BEDGES, GBASE, ROWSTART, DINV, CSRSRC, N);

  // ---- x -> bf16, weight fragment packing (single launch)
  int n4 = N * 128 / 4;
  f2b_kernel<<<(n4 + 255) / 256, 256, 0, stream>>>(x, XB, n4);
  packw_all_kernel<<<312, 256, 0, stream>>>(W_l1, W_r1, W_l2, W_r2, W_out,
                                            WB1, WB2, WBO);

  int lblocks = (N + 63) / 64;
  sage1_kernel<<<lblocks, 256, 0, stream>>>(XB, CSRSRC, ROWSTART, DINV,
                                            WB1, b_l1, HB, N);
  sage2_kernel<<<lblocks, 256, 0, stream>>>(HB, CSRSRC, ROWSTART, DINV,
                                            WB2, b_l2, WBO, b_out,
                                            (float*)d_out, N);
}

// Round 6
// 341.995 us; speedup vs baseline: 1.3582x; 1.3582x over previous
//
#include <hip/hip_runtime.h>
#include <hip/hip_bf16.h>

#define HID 128
#define OUT_DIM 112
#define CAP 4096

typedef short bf16x8 __attribute__((ext_vector_type(8)));
typedef float f32x4 __attribute__((ext_vector_type(4)));

__device__ __forceinline__ ushort f2b(float f) {
  __hip_bfloat16 h = __float2bfloat16(f);  // RNE
  return *reinterpret_cast<ushort*>(&h);
}
__device__ __forceinline__ float blo(uint u) { return __uint_as_float(u << 16); }
__device__ __forceinline__ float bhi(uint u) { return __uint_as_float(u & 0xffff0000u); }

// ---- fp32 -> bf16 bulk convert (4 elems/thread)
__global__ __launch_bounds__(256) void f2b_kernel(
    const float* __restrict__ in, ushort* __restrict__ out, int n4) {
  int i = blockIdx.x * 256 + threadIdx.x;
  if (i >= n4) return;
  float4 v = ((const float4*)in)[i];
  ushort4 r;
  r.x = f2b(v.x); r.y = f2b(v.y); r.z = f2b(v.z); r.w = f2b(v.w);
  ((ushort4*)out)[i] = r;
}

// ---- pack all 5 weight matrices into MFMA B-fragment order in ONE launch.
// wb[ks][nt][lane][j] = bf16( W[nt*16 + (lane&15)][ks*32 + (lane>>4)*8 + j] )
__global__ __launch_bounds__(256) void packw_all_kernel(
    const float* __restrict__ Wl1, const float* __restrict__ Wr1,
    const float* __restrict__ Wl2, const float* __restrict__ Wr2,
    const float* __restrict__ Wo, ushort* __restrict__ WB1,
    ushort* __restrict__ WB2, ushort* __restrict__ WBO) {
  int p = blockIdx.x * 256 + threadIdx.x;  // 0..79871
  const float* W;
  ushort* wb;
  int ntiles, off;
  if (p < 16384)      { W = Wl1; wb = WB1;         ntiles = 8; off = p; }
  else if (p < 32768) { W = Wr1; wb = WB1 + 16384; ntiles = 8; off = p - 16384; }
  else if (p < 49152) { W = Wl2; wb = WB2;         ntiles = 8; off = p - 32768; }
  else if (p < 65536) { W = Wr2; wb = WB2 + 16384; ntiles = 8; off = p - 49152; }
  else if (p < 79872) { W = Wo;  wb = WBO;         ntiles = 7; off = p - 65536; }
  else return;
  int j = off & 7;
  int l = (off >> 3) & 63;
  int rest = off >> 9;
  int nt = rest % ntiles;
  int ks = rest / ntiles;
  int nn = nt * 16 + (l & 15);
  int k = ks * 32 + (l >> 4) * 8 + j;
  wb[off] = f2b(W[nn * 128 + k]);
}

// ---- sort pass 0: per-block LDS histogram of dst>>7, merged to global
__global__ __launch_bounds__(256) void hist_kernel(
    const int* __restrict__ dst, int* __restrict__ gcount, int e, int nb) {
  __shared__ int lh[1024];
  const int t = threadIdx.x;
  for (int i = t; i < nb; i += 256) lh[i] = 0;
  __syncthreads();
  int base = blockIdx.x * 4096;
#pragma unroll
  for (int j = 0; j < 16; ++j) {
    int i = base + j * 256 + t;
    if (i < e) atomicAdd(&lh[dst[i] >> 7], 1);
  }
  __syncthreads();
  for (int i = t; i < nb; i += 256)
    if (lh[i]) atomicAdd(&gcount[i], lh[i]);
}

// ---- sort pass 1: scan bucket counts -> bases + cursors; rowstart[n]=e
__global__ __launch_bounds__(1024) void scan_nb_kernel(
    const int* __restrict__ gcount, int* __restrict__ gbase,
    int* __restrict__ gcursor, int* __restrict__ rowstart,
    int e, int n, int nb) {
  __shared__ int wsum[16];
  const int t = threadIdx.x, lane = t & 63, wid = t >> 6;
  int v = (t < nb) ? gcount[t] : 0;
  int s = v;
#pragma unroll
  for (int off = 1; off < 64; off <<= 1) {
    int u = __shfl_up(s, off, 64);
    if (lane >= off) s += u;
  }
  if (lane == 63) wsum[wid] = s;
  __syncthreads();
  if (wid == 0) {
    int ws = (lane < 16) ? wsum[lane] : 0;
#pragma unroll
    for (int off = 1; off < 16; off <<= 1) {
      int u = __shfl_up(ws, off, 64);
      if (lane >= off) ws += u;
    }
    if (lane < 16) wsum[lane] = ws;
  }
  __syncthreads();
  int excl = s - v + (wid ? wsum[wid - 1] : 0);
  if (t < nb) {
    gbase[t] = excl;
    gcursor[t] = excl;
  }
  if (t == 0) {
    gbase[nb] = e;
    rowstart[n] = e;
  }
}

// ---- sort pass 2: bucket edges; write packed (src<<7)|(dst&127)
__global__ __launch_bounds__(1024) void bucket_scatter_kernel(
    const int* __restrict__ src, const int* __restrict__ dst,
    int* __restrict__ gcursor, uint* __restrict__ bedges, int e, int nb) {
  __shared__ int lh[1024];
  __shared__ int lstart[1024];
  __shared__ int wsum[16];
  __shared__ uint sp[8192];
  __shared__ ushort sb[8192];
  const int t = threadIdx.x, lane = t & 63, wid = t >> 6;
  const int base = blockIdx.x * 8192;
  const int ecnt = min(8192, e - base);
  for (int i = t; i < nb; i += 1024) lh[i] = 0;
  __syncthreads();
  int myb[8], myr[8];
  uint myp[8];
#pragma unroll
  for (int j = 0; j < 8; ++j) {
    int i = base + j * 1024 + t;
    myb[j] = -1;
    if (i < e) {
      int d = dst[i];
      int sv = src[i];
      int b = d >> 7;
      myb[j] = b;
      myp[j] = ((uint)sv << 7) | (uint)(d & 127);
      myr[j] = atomicAdd(&lh[b], 1);
    }
  }
  __syncthreads();
  int cnt = (t < nb) ? lh[t] : 0;
  int s = cnt;
#pragma unroll
  for (int off = 1; off < 64; off <<= 1) {
    int u = __shfl_up(s, off, 64);
    if (lane >= off) s += u;
  }
  if (lane == 63) wsum[wid] = s;
  __syncthreads();
  if (wid == 0) {
    int ws = (lane < 16) ? wsum[lane] : 0;
#pragma unroll
    for (int off = 1; off < 16; off <<= 1) {
      int u = __shfl_up(ws, off, 64);
      if (lane >= off) ws += u;
    }
    if (lane < 16) wsum[lane] = ws;
  }
  __syncthreads();
  int excl = s - cnt + (wid ? wsum[wid - 1] : 0);
  if (t < nb) lstart[t] = excl;
  __syncthreads();
  if (t < nb) lh[t] = (cnt > 0) ? atomicAdd(&gcursor[t], cnt) : 0;
  __syncthreads();
#pragma unroll
  for (int j = 0; j < 8; ++j) {
    if (myb[j] >= 0) {
      int slot = lstart[myb[j]] + myr[j];
      sp[slot] = myp[j];
      sb[slot] = (ushort)myb[j];
    }
  }
  __syncthreads();
#pragma unroll
  for (int j = 0; j < 8; ++j) {
    int i = j * 1024 + t;
    if (i < ecnt) {
      int b = sb[i];
      int pos = lh[b] + (i - lstart[b]);
      bedges[pos] = sp[i];
    }
  }
}

// ---- sort pass 3: per-bucket counting sort by dst&127 -> csr_src, rowstart, dinv
__global__ __launch_bounds__(256) void csr_build_kernel(
    const uint* __restrict__ bedges, const int* __restrict__ gbase,
    int* __restrict__ rowstart, float* __restrict__ dinv,
    int* __restrict__ csr_src, int n) {
  __shared__ int lh[128];
  __shared__ int lst[128];
  __shared__ int lcur[128];
  __shared__ int wsum2[4];
  __shared__ int lsorted[CAP];
  const int t = threadIdx.x;
  const int bkt = blockIdx.x;
  const int node0 = bkt << 7;
  const int g0 = gbase[bkt], g1 = gbase[bkt + 1];
  const int cnt = g1 - g0;
  if (t < 128) lh[t] = 0;
  __syncthreads();
  for (int i = t; i < cnt; i += 256)
    atomicAdd(&lh[bedges[g0 + i] & 127], 1);
  __syncthreads();
  const int lane = t & 63, wid = t >> 6;
  int v = (t < 128) ? lh[t] : 0;
  int s = v;
#pragma unroll
  for (int off = 1; off < 64; off <<= 1) {
    int u = __shfl_up(s, off, 64);
    if (lane >= off) s += u;
  }
  if (t < 128 && lane == 63) wsum2[wid] = s;
  __syncthreads();
  int excl = s - v + ((wid == 1) ? wsum2[0] : 0);
  if (t < 128) {
    lst[t] = excl;
    lcur[t] = excl;
    int node = node0 + t;
    if (node < n) {
      rowstart[node] = g0 + excl;
      dinv[node] = 1.0f / (float)max(v, 1);
    }
  }
  __syncthreads();
  for (int i = t; i < cnt; i += 256) {
    uint p = bedges[g0 + i];
    int d = p & 127;
    int slot = atomicAdd(&lcur[d], 1);
    int sv = (int)(p >> 7);
    if (slot < CAP) lsorted[slot] = sv;
    else csr_src[g0 + slot] = sv;
  }
  __syncthreads();
  int lim = min(cnt, CAP);
  for (int i = t; i < lim; i += 256) csr_src[g0 + i] = lsorted[i];
}

// ---- gather-mean aggregation, wide: one wave/node, uint4 (8 bf16)/lane,
// 16 lanes cover a 256 B row, 4 edge slots in flight per wave.
__global__ __launch_bounds__(256) void agg_bf16_kernel(
    const ushort* __restrict__ xb, const int* __restrict__ csr_src,
    const int* __restrict__ rowstart, const float* __restrict__ dinv,
    ushort* __restrict__ aggb, int n) {
  int node = blockIdx.x * 4 + (threadIdx.x >> 6);
  int lane = threadIdx.x & 63;
  if (node >= n) return;
  int s = rowstart[node], e1 = rowstart[node + 1];
  const int c = lane & 15;      // 16B column chunk
  const int eslot = lane >> 4;  // 4 edges concurrently
  float a0 = 0.f, a1 = 0.f, a2 = 0.f, a3 = 0.f;
  float a4 = 0.f, a5 = 0.f, a6 = 0.f, a7 = 0.f;
#pragma unroll 2
  for (int e = s + eslot; e < e1; e += 4) {
    int sv = csr_src[e];
    uint4 u = ((const uint4*)(xb + (size_t)sv * 128))[c];
    a0 += blo(u.x); a1 += bhi(u.x);
    a2 += blo(u.y); a3 += bhi(u.y);
    a4 += blo(u.z); a5 += bhi(u.z);
    a6 += blo(u.w); a7 += bhi(u.w);
  }
  // combine the 4 edge slots
  a0 += __shfl_xor(a0, 16, 64); a1 += __shfl_xor(a1, 16, 64);
  a2 += __shfl_xor(a2, 16, 64); a3 += __shfl_xor(a3, 16, 64);
  a4 += __shfl_xor(a4, 16, 64); a5 += __shfl_xor(a5, 16, 64);
  a6 += __shfl_xor(a6, 16, 64); a7 += __shfl_xor(a7, 16, 64);
  a0 += __shfl_xor(a0, 32, 64); a1 += __shfl_xor(a1, 32, 64);
  a2 += __shfl_xor(a2, 32, 64); a3 += __shfl_xor(a3, 32, 64);
  a4 += __shfl_xor(a4, 32, 64); a5 += __shfl_xor(a5, 32, 64);
  a6 += __shfl_xor(a6, 32, 64); a7 += __shfl_xor(a7, 32, 64);
  if (eslot == 0) {
    float sc = dinv[node];
    uint4 r;
    r.x = (uint)f2b(a0 * sc) | ((uint)f2b(a1 * sc) << 16);
    r.y = (uint)f2b(a2 * sc) | ((uint)f2b(a3 * sc) << 16);
    r.z = (uint)f2b(a4 * sc) | ((uint)f2b(a5 * sc) << 16);
    r.w = (uint)f2b(a6 * sc) | ((uint)f2b(a7 * sc) << 16);
    ((uint4*)(aggb + (size_t)node * 128))[c] = r;
  }
}

// ---- fused SAGE linear via MFMA (bf16 in, fp32 acc, bf16 out)
__global__ __launch_bounds__(256) void lin_mfma_kernel(
    const ushort* __restrict__ meanb, const ushort* __restrict__ xb,
    const ushort* __restrict__ wb, const float* __restrict__ bias,
    ushort* __restrict__ outb, int n) {
  __shared__ ushort zA[64 * 128];
  __shared__ ushort zX[64 * 128];
  const int t = threadIdx.x;
  const int block0 = blockIdx.x * 64;
#pragma unroll
  for (int i = 0; i < 4; ++i) {
    int c = i * 256 + t;
    int row = c >> 4;
    int col = c & 15;
    int node = block0 + row;
    int4 va = make_int4(0, 0, 0, 0), vx = make_int4(0, 0, 0, 0);
    if (node < n) {
      va = ((const int4*)(meanb + (size_t)node * 128))[col];
      vx = ((const int4*)(xb + (size_t)node * 128))[col];
    }
    ((int4*)zA)[c] = va;
    ((int4*)zX)[c] = vx;
  }
  __syncthreads();
  const int lane = t & 63;
  const int wave = t >> 6;
  const int m0 = wave * 16;
  const int cidx = lane & 15;
  const int quad = lane >> 4;
  f32x4 acc[8];
#pragma unroll
  for (int nt = 0; nt < 8; ++nt) acc[nt] = (f32x4){0.f, 0.f, 0.f, 0.f};
#pragma unroll
  for (int s = 0; s < 2; ++s) {
    const ushort* zs = (s == 0) ? zA : zX;
#pragma unroll
    for (int ks = 0; ks < 4; ++ks) {
      bf16x8 a = *(const bf16x8*)(zs + (m0 + cidx) * 128 + ks * 32 + quad * 8);
      const ushort* wp = wb + ((size_t)((s * 4 + ks) * 8) * 64 + lane) * 8;
#pragma unroll
      for (int nt = 0; nt < 8; ++nt) {
        bf16x8 b = *(const bf16x8*)(wp + nt * 512);
        acc[nt] = __builtin_amdgcn_mfma_f32_16x16x32_bf16(a, b, acc[nt], 0, 0, 0);
      }
    }
  }
  __syncthreads();
#pragma unroll
  for (int nt = 0; nt < 8; ++nt) {
    float bv = bias[nt * 16 + cidx];
#pragma unroll
    for (int i = 0; i < 4; ++i) {
      float v = fmaxf(acc[nt][i] + bv, 0.f);
      zA[(m0 + quad * 4 + i) * 128 + nt * 16 + cidx] = f2b(v);
    }
  }
  __syncthreads();
#pragma unroll
  for (int i = 0; i < 4; ++i) {
    int c = i * 256 + t;
    int row = c >> 4;
    int col = c & 15;
    int node = block0 + row;
    if (node < n) ((int4*)(outb + (size_t)node * 128))[col] = ((const int4*)zA)[c];
  }
}

// ---- output projection via MFMA: out = h2 @ W_out^T + b_out, fp32 [n x 112]
__global__ __launch_bounds__(256) void out_mfma_kernel(
    const ushort* __restrict__ h2b, const ushort* __restrict__ wb,
    const float* __restrict__ bias, float* __restrict__ outp, int n) {
  __shared__ ushort zt[64 * 128];
  __shared__ float zo[64 * 112];
  const int t = threadIdx.x;
  const int block0 = blockIdx.x * 64;
#pragma unroll
  for (int i = 0; i < 4; ++i) {
    int c = i * 256 + t;
    int row = c >> 4;
    int col = c & 15;
    int node = block0 + row;
    int4 v = make_int4(0, 0, 0, 0);
    if (node < n) v = ((const int4*)(h2b + (size_t)node * 128))[col];
    ((int4*)zt)[c] = v;
  }
  __syncthreads();
  const int lane = t & 63;
  const int wave = t >> 6;
  const int m0 = wave * 16;
  const int cidx = lane & 15;
  const int quad = lane >> 4;
  f32x4 acc[7];
#pragma unroll
  for (int nt = 0; nt < 7; ++nt) acc[nt] = (f32x4){0.f, 0.f, 0.f, 0.f};
#pragma unroll
  for (int ks = 0; ks < 4; ++ks) {
    bf16x8 a = *(const bf16x8*)(zt + (m0 + cidx) * 128 + ks * 32 + quad * 8);
    const ushort* wp = wb + ((size_t)(ks * 7) * 64 + lane) * 8;
#pragma unroll
    for (int nt = 0; nt < 7; ++nt) {
      bf16x8 b = *(const bf16x8*)(wp + nt * 512);
      acc[nt] = __builtin_amdgcn_mfma_f32_16x16x32_bf16(a, b, acc[nt], 0, 0, 0);
    }
  }
#pragma unroll
  for (int nt = 0; nt < 7; ++nt) {
    float bv = bias[nt * 16 + cidx];
#pragma unroll
    for (int i = 0; i < 4; ++i)
      zo[(m0 + quad * 4 + i) * 112 + nt * 16 + cidx] = acc[nt][i] + bv;
  }
  __syncthreads();
#pragma unroll
  for (int i = 0; i < 7; ++i) {
    int c = i * 256 + t;
    int node = block0 + c / 28;
    if (node < n)
      ((float4*)(outp + (size_t)block0 * 112))[c] = ((const float4*)zo)[c];
  }
}

extern "C" void kernel_launch(void* const* d_in, const int* in_sizes, int n_in,
                              void* d_out, int out_size, void* d_ws, size_t ws_size,
                              hipStream_t stream) {
  const float* x     = (const float*)d_in[0];
  const int*   ei    = (const int*)d_in[1];
  const float* W_l1  = (const float*)d_in[2];
  const float* b_l1  = (const float*)d_in[3];
  const float* W_r1  = (const float*)d_in[4];
  const float* W_l2  = (const float*)d_in[5];
  const float* b_l2  = (const float*)d_in[6];
  const float* W_r2  = (const float*)d_in[7];
  const float* W_out = (const float*)d_in[8];
  const float* b_out = (const float*)d_in[9];

  const int N = in_sizes[0] / 128;
  const int E = in_sizes[1] / 2;
  const int NB = (N + 127) >> 7;
  const int* src = ei;
  const int* dst = ei + E;

  ushort* XB = (ushort*)d_ws;               // N*128 bf16 (x, later h2)
  ushort* MB = XB + (size_t)N * 128;        // N*128 bf16 (mean)
  ushort* HB = MB + (size_t)N * 128;        // N*128 bf16 (h1)
  float* DINV = (float*)(HB + (size_t)N * 128);  // N f32
  ushort* WB1 = (ushort*)(DINV + N);        // 32768
  ushort* WB2 = WB1 + 32768;                // 32768
  ushort* WBO = WB2 + 32768;                // 14336
  int* GCOUNT   = (int*)(WBO + 14336);      // NB
  int* GBASE    = GCOUNT + NB;              // NB+1
  int* GCURSOR  = GBASE + NB + 1;           // NB
  int* ROWSTART = GCURSOR + NB;             // N+1
  uint* BEDGES  = (uint*)(ROWSTART + N + 1);// E
  int* CSRSRC   = (int*)(BEDGES + E);       // E

  // ---- CSR build via two-pass counting sort
  hipMemsetAsync(GCOUNT, 0, (size_t)NB * sizeof(int), stream);
  hist_kernel<<<(E + 4095) / 4096, 256, 0, stream>>>(dst, GCOUNT, E, NB);
  scan_nb_kernel<<<1, 1024, 0, stream>>>(GCOUNT, GBASE, GCURSOR, ROWSTART, E, N, NB);
  bucket_scatter_kernel<<<(E + 8191) / 8192, 1024, 0, stream>>>(
      src, dst, GCURSOR, BEDGES, E, NB);
  csr_build_kernel<<<NB, 256, 0, stream>>>(BEDGES, GBASE, ROWSTART, DINV, CSRSRC, N);

  // ---- x -> bf16, weight fragment packing (single launch)
  int n4 = N * 128 / 4;
  f2b_kernel<<<(n4 + 255) / 256, 256, 0, stream>>>(x, XB, n4);
  packw_all_kernel<<<312, 256, 0, stream>>>(W_l1, W_r1, W_l2, W_r2, W_out,
                                            WB1, WB2, WBO);

  int ablocks = (N + 3) / 4;
  int lblocks = (N + 63) / 64;

  // layer 1
  agg_bf16_kernel<<<ablocks, 256, 0, stream>>>(XB, CSRSRC, ROWSTART, DINV, MB, N);
  lin_mfma_kernel<<<lblocks, 256, 0, stream>>>(MB, XB, WB1, b_l1, HB, N);

  // layer 2 (h2 -> XB; x no longer needed)
  agg_bf16_kernel<<<ablocks, 256, 0, stream>>>(HB, CSRSRC, ROWSTART, DINV, MB, N);
  lin_mfma_kernel<<<lblocks, 256, 0, stream>>>(MB, HB, WB2, b_l2, XB, N);

  // output projection
  out_mfma_kernel<<<lblocks, 256, 0, stream>>>(XB, WBO, b_out, (float*)d_out, N);
}

// Round 7
// 330.143 us; speedup vs baseline: 1.4070x; 1.0359x over previous
//
#include <hip/hip_runtime.h>
#include <hip/hip_bf16.h>

#define HID 128
#define OUT_DIM 112
#define CAP 4096

typedef short bf16x8 __attribute__((ext_vector_type(8)));
typedef float f32x4 __attribute__((ext_vector_type(4)));

__device__ __forceinline__ ushort f2b(float f) {
  __hip_bfloat16 h = __float2bfloat16(f);  // RNE
  return *reinterpret_cast<ushort*>(&h);
}
__device__ __forceinline__ float blo(uint u) { return __uint_as_float(u << 16); }
__device__ __forceinline__ float bhi(uint u) { return __uint_as_float(u & 0xffff0000u); }

// ---- merged prep: f2b (x->bf16) + dst histogram + weight fragment packing.
// Grid sections: [0,f2b_blocks) f2b, [f2b_blocks, +hist_blocks) hist, rest packw.
__global__ __launch_bounds__(256) void prep_kernel(
    const float* __restrict__ x, ushort* __restrict__ xb, int n4,
    const int* __restrict__ dst, int* __restrict__ gcount, int e, int nb,
    const float* __restrict__ Wl1, const float* __restrict__ Wr1,
    const float* __restrict__ Wl2, const float* __restrict__ Wr2,
    const float* __restrict__ Wo, ushort* __restrict__ WB1,
    ushort* __restrict__ WB2, ushort* __restrict__ WBO,
    int f2b_blocks, int hist_blocks) {
  __shared__ int lh[1024];
  const int b = blockIdx.x;
  const int t = threadIdx.x;
  if (b < f2b_blocks) {
    int i = b * 256 + t;
    if (i < n4) {
      float4 v = ((const float4*)x)[i];
      ushort4 r;
      r.x = f2b(v.x); r.y = f2b(v.y); r.z = f2b(v.z); r.w = f2b(v.w);
      ((ushort4*)xb)[i] = r;
    }
    return;
  }
  if (b < f2b_blocks + hist_blocks) {
    for (int i = t; i < nb; i += 256) lh[i] = 0;
    __syncthreads();
    int base = (b - f2b_blocks) * 4096;
#pragma unroll
    for (int j = 0; j < 16; ++j) {
      int i = base + j * 256 + t;
      if (i < e) atomicAdd(&lh[dst[i] >> 7], 1);
    }
    __syncthreads();
    for (int i = t; i < nb; i += 256)
      if (lh[i]) atomicAdd(&gcount[i], lh[i]);
    return;
  }
  int p = (b - f2b_blocks - hist_blocks) * 256 + t;  // 0..79871
  const float* W;
  ushort* wb;
  int ntiles, off;
  if (p < 16384)      { W = Wl1; wb = WB1;         ntiles = 8; off = p; }
  else if (p < 32768) { W = Wr1; wb = WB1 + 16384; ntiles = 8; off = p - 16384; }
  else if (p < 49152) { W = Wl2; wb = WB2;         ntiles = 8; off = p - 32768; }
  else if (p < 65536) { W = Wr2; wb = WB2 + 16384; ntiles = 8; off = p - 49152; }
  else if (p < 79872) { W = Wo;  wb = WBO;         ntiles = 7; off = p - 65536; }
  else return;
  int j = off & 7;
  int l = (off >> 3) & 63;
  int rest = off >> 9;
  int nt = rest % ntiles;
  int ks = rest / ntiles;
  int nn = nt * 16 + (l & 15);
  int k = ks * 32 + (l >> 4) * 8 + j;
  wb[off] = f2b(W[nn * 128 + k]);
}

// ---- sort pass 1: scan bucket counts -> bases + cursors; rowstart[n]=e
__global__ __launch_bounds__(1024) void scan_nb_kernel(
    const int* __restrict__ gcount, int* __restrict__ gbase,
    int* __restrict__ gcursor, int* __restrict__ rowstart,
    int e, int n, int nb) {
  __shared__ int wsum[16];
  const int t = threadIdx.x, lane = t & 63, wid = t >> 6;
  int v = (t < nb) ? gcount[t] : 0;
  int s = v;
#pragma unroll
  for (int off = 1; off < 64; off <<= 1) {
    int u = __shfl_up(s, off, 64);
    if (lane >= off) s += u;
  }
  if (lane == 63) wsum[wid] = s;
  __syncthreads();
  if (wid == 0) {
    int ws = (lane < 16) ? wsum[lane] : 0;
#pragma unroll
    for (int off = 1; off < 16; off <<= 1) {
      int u = __shfl_up(ws, off, 64);
      if (lane >= off) ws += u;
    }
    if (lane < 16) wsum[lane] = ws;
  }
  __syncthreads();
  int excl = s - v + (wid ? wsum[wid - 1] : 0);
  if (t < nb) {
    gbase[t] = excl;
    gcursor[t] = excl;
  }
  if (t == 0) {
    gbase[nb] = e;
    rowstart[n] = e;
  }
}

// ---- sort pass 2: bucket edges; write packed (src<<7)|(dst&127)
__global__ __launch_bounds__(1024) void bucket_scatter_kernel(
    const int* __restrict__ src, const int* __restrict__ dst,
    int* __restrict__ gcursor, uint* __restrict__ bedges, int e, int nb) {
  __shared__ int lh[1024];
  __shared__ int lstart[1024];
  __shared__ int wsum[16];
  __shared__ uint sp[8192];
  __shared__ ushort sb[8192];
  const int t = threadIdx.x, lane = t & 63, wid = t >> 6;
  const int base = blockIdx.x * 8192;
  const int ecnt = min(8192, e - base);
  for (int i = t; i < nb; i += 1024) lh[i] = 0;
  __syncthreads();
  int myb[8], myr[8];
  uint myp[8];
#pragma unroll
  for (int j = 0; j < 8; ++j) {
    int i = base + j * 1024 + t;
    myb[j] = -1;
    if (i < e) {
      int d = dst[i];
      int sv = src[i];
      int b = d >> 7;
      myb[j] = b;
      myp[j] = ((uint)sv << 7) | (uint)(d & 127);
      myr[j] = atomicAdd(&lh[b], 1);
    }
  }
  __syncthreads();
  int cnt = (t < nb) ? lh[t] : 0;
  int s = cnt;
#pragma unroll
  for (int off = 1; off < 64; off <<= 1) {
    int u = __shfl_up(s, off, 64);
    if (lane >= off) s += u;
  }
  if (lane == 63) wsum[wid] = s;
  __syncthreads();
  if (wid == 0) {
    int ws = (lane < 16) ? wsum[lane] : 0;
#pragma unroll
    for (int off = 1; off < 16; off <<= 1) {
      int u = __shfl_up(ws, off, 64);
      if (lane >= off) ws += u;
    }
    if (lane < 16) wsum[lane] = ws;
  }
  __syncthreads();
  int excl = s - cnt + (wid ? wsum[wid - 1] : 0);
  if (t < nb) lstart[t] = excl;
  __syncthreads();
  if (t < nb) lh[t] = (cnt > 0) ? atomicAdd(&gcursor[t], cnt) : 0;
  __syncthreads();
#pragma unroll
  for (int j = 0; j < 8; ++j) {
    if (myb[j] >= 0) {
      int slot = lstart[myb[j]] + myr[j];
      sp[slot] = myp[j];
      sb[slot] = (ushort)myb[j];
    }
  }
  __syncthreads();
#pragma unroll
  for (int j = 0; j < 8; ++j) {
    int i = j * 1024 + t;
    if (i < ecnt) {
      int b = sb[i];
      int pos = lh[b] + (i - lstart[b]);
      bedges[pos] = sp[i];
    }
  }
}

// ---- sort pass 3: per-bucket counting sort by dst&127 -> csr_src, rowstart, dinv
__global__ __launch_bounds__(256) void csr_build_kernel(
    const uint* __restrict__ bedges, const int* __restrict__ gbase,
    int* __restrict__ rowstart, float* __restrict__ dinv,
    int* __restrict__ csr_src, int n) {
  __shared__ int lh[128];
  __shared__ int lst[128];
  __shared__ int lcur[128];
  __shared__ int wsum2[4];
  __shared__ int lsorted[CAP];
  const int t = threadIdx.x;
  const int bkt = blockIdx.x;
  const int node0 = bkt << 7;
  const int g0 = gbase[bkt], g1 = gbase[bkt + 1];
  const int cnt = g1 - g0;
  if (t < 128) lh[t] = 0;
  __syncthreads();
  for (int i = t; i < cnt; i += 256)
    atomicAdd(&lh[bedges[g0 + i] & 127], 1);
  __syncthreads();
  const int lane = t & 63, wid = t >> 6;
  int v = (t < 128) ? lh[t] : 0;
  int s = v;
#pragma unroll
  for (int off = 1; off < 64; off <<= 1) {
    int u = __shfl_up(s, off, 64);
    if (lane >= off) s += u;
  }
  if (t < 128 && lane == 63) wsum2[wid] = s;
  __syncthreads();
  int excl = s - v + ((wid == 1) ? wsum2[0] : 0);
  if (t < 128) {
    lst[t] = excl;
    lcur[t] = excl;
    int node = node0 + t;
    if (node < n) {
      rowstart[node] = g0 + excl;
      dinv[node] = 1.0f / (float)max(v, 1);
    }
  }
  __syncthreads();
  for (int i = t; i < cnt; i += 256) {
    uint p = bedges[g0 + i];
    int d = p & 127;
    int slot = atomicAdd(&lcur[d], 1);
    int sv = (int)(p >> 7);
    if (slot < CAP) lsorted[slot] = sv;
    else csr_src[g0 + slot] = sv;
  }
  __syncthreads();
  int lim = min(cnt, CAP);
  for (int i = t; i < lim; i += 256) csr_src[g0 + i] = lsorted[i];
}

// ---- gather-mean aggregation, deep-MLP: one wave/node, uint4/lane,
// 16 lanes/row, 4 edge slots x 4-deep pipelined loads = 16 edges in flight.
__global__ __launch_bounds__(256) void agg_bf16_kernel(
    const ushort* __restrict__ xb, const int* __restrict__ csr_src,
    const int* __restrict__ rowstart, const float* __restrict__ dinv,
    ushort* __restrict__ aggb, int n) {
  int node = blockIdx.x * 4 + (threadIdx.x >> 6);
  int lane = threadIdx.x & 63;
  if (node >= n) return;
  int s = rowstart[node], e1 = rowstart[node + 1];
  const int c = lane & 15;      // 16B column chunk
  const int eslot = lane >> 4;  // 4 edges concurrently
  float a0 = 0.f, a1 = 0.f, a2 = 0.f, a3 = 0.f;
  float a4 = 0.f, a5 = 0.f, a6 = 0.f, a7 = 0.f;
  int e = s + eslot;
  for (; e + 12 < e1; e += 16) {
    int s0 = csr_src[e];
    int s1 = csr_src[e + 4];
    int s2 = csr_src[e + 8];
    int s3 = csr_src[e + 12];
    uint4 u0 = ((const uint4*)(xb + (size_t)s0 * 128))[c];
    uint4 u1 = ((const uint4*)(xb + (size_t)s1 * 128))[c];
    uint4 u2 = ((const uint4*)(xb + (size_t)s2 * 128))[c];
    uint4 u3 = ((const uint4*)(xb + (size_t)s3 * 128))[c];
    a0 += (blo(u0.x) + blo(u1.x)) + (blo(u2.x) + blo(u3.x));
    a1 += (bhi(u0.x) + bhi(u1.x)) + (bhi(u2.x) + bhi(u3.x));
    a2 += (blo(u0.y) + blo(u1.y)) + (blo(u2.y) + blo(u3.y));
    a3 += (bhi(u0.y) + bhi(u1.y)) + (bhi(u2.y) + bhi(u3.y));
    a4 += (blo(u0.z) + blo(u1.z)) + (blo(u2.z) + blo(u3.z));
    a5 += (bhi(u0.z) + bhi(u1.z)) + (bhi(u2.z) + bhi(u3.z));
    a6 += (blo(u0.w) + blo(u1.w)) + (blo(u2.w) + blo(u3.w));
    a7 += (bhi(u0.w) + bhi(u1.w)) + (bhi(u2.w) + bhi(u3.w));
  }
  for (; e < e1; e += 4) {
    int sv = csr_src[e];
    uint4 u = ((const uint4*)(xb + (size_t)sv * 128))[c];
    a0 += blo(u.x); a1 += bhi(u.x);
    a2 += blo(u.y); a3 += bhi(u.y);
    a4 += blo(u.z); a5 += bhi(u.z);
    a6 += blo(u.w); a7 += bhi(u.w);
  }
  // combine the 4 edge slots
  a0 += __shfl_xor(a0, 16, 64); a1 += __shfl_xor(a1, 16, 64);
  a2 += __shfl_xor(a2, 16, 64); a3 += __shfl_xor(a3, 16, 64);
  a4 += __shfl_xor(a4, 16, 64); a5 += __shfl_xor(a5, 16, 64);
  a6 += __shfl_xor(a6, 16, 64); a7 += __shfl_xor(a7, 16, 64);
  a0 += __shfl_xor(a0, 32, 64); a1 += __shfl_xor(a1, 32, 64);
  a2 += __shfl_xor(a2, 32, 64); a3 += __shfl_xor(a3, 32, 64);
  a4 += __shfl_xor(a4, 32, 64); a5 += __shfl_xor(a5, 32, 64);
  a6 += __shfl_xor(a6, 32, 64); a7 += __shfl_xor(a7, 32, 64);
  if (eslot == 0) {
    float sc = dinv[node];
    uint4 r;
    r.x = (uint)f2b(a0 * sc) | ((uint)f2b(a1 * sc) << 16);
    r.y = (uint)f2b(a2 * sc) | ((uint)f2b(a3 * sc) << 16);
    r.z = (uint)f2b(a4 * sc) | ((uint)f2b(a5 * sc) << 16);
    r.w = (uint)f2b(a6 * sc) | ((uint)f2b(a7 * sc) << 16);
    ((uint4*)(aggb + (size_t)node * 128))[c] = r;
  }
}

// ---- fused SAGE linear via MFMA (bf16 in, fp32 acc, bf16 out) — layer 1
__global__ __launch_bounds__(256) void lin_mfma_kernel(
    const ushort* __restrict__ meanb, const ushort* __restrict__ xb,
    const ushort* __restrict__ wb, const float* __restrict__ bias,
    ushort* __restrict__ outb, int n) {
  __shared__ ushort zA[64 * 128];
  __shared__ ushort zX[64 * 128];
  const int t = threadIdx.x;
  const int block0 = blockIdx.x * 64;
#pragma unroll
  for (int i = 0; i < 4; ++i) {
    int c = i * 256 + t;
    int row = c >> 4;
    int col = c & 15;
    int node = block0 + row;
    int4 va = make_int4(0, 0, 0, 0), vx = make_int4(0, 0, 0, 0);
    if (node < n) {
      va = ((const int4*)(meanb + (size_t)node * 128))[col];
      vx = ((const int4*)(xb + (size_t)node * 128))[col];
    }
    ((int4*)zA)[c] = va;
    ((int4*)zX)[c] = vx;
  }
  __syncthreads();
  const int lane = t & 63;
  const int wave = t >> 6;
  const int m0 = wave * 16;
  const int cidx = lane & 15;
  const int quad = lane >> 4;
  f32x4 acc[8];
#pragma unroll
  for (int nt = 0; nt < 8; ++nt) acc[nt] = (f32x4){0.f, 0.f, 0.f, 0.f};
#pragma unroll
  for (int s = 0; s < 2; ++s) {
    const ushort* zs = (s == 0) ? zA : zX;
#pragma unroll
    for (int ks = 0; ks < 4; ++ks) {
      bf16x8 a = *(const bf16x8*)(zs + (m0 + cidx) * 128 + ks * 32 + quad * 8);
      const ushort* wp = wb + ((size_t)((s * 4 + ks) * 8) * 64 + lane) * 8;
#pragma unroll
      for (int nt = 0; nt < 8; ++nt) {
        bf16x8 b = *(const bf16x8*)(wp + nt * 512);
        acc[nt] = __builtin_amdgcn_mfma_f32_16x16x32_bf16(a, b, acc[nt], 0, 0, 0);
      }
    }
  }
  __syncthreads();
#pragma unroll
  for (int nt = 0; nt < 8; ++nt) {
    float bv = bias[nt * 16 + cidx];
#pragma unroll
    for (int i = 0; i < 4; ++i) {
      float v = fmaxf(acc[nt][i] + bv, 0.f);
      zA[(m0 + quad * 4 + i) * 128 + nt * 16 + cidx] = f2b(v);
    }
  }
  __syncthreads();
#pragma unroll
  for (int i = 0; i < 4; ++i) {
    int c = i * 256 + t;
    int row = c >> 4;
    int col = c & 15;
    int node = block0 + row;
    if (node < n) ((int4*)(outb + (size_t)node * 128))[col] = ((const int4*)zA)[c];
  }
}

// ---- fused layer-2 linear + output projection:
// h2 = relu([mean|h1] MFMA + b) kept in per-wave-private LDS rows,
// then out = h2 @ Wout^T + b_out -> fp32 d_out via LDS-staged coalesced store.
__global__ __launch_bounds__(256) void lin2out_kernel(
    const ushort* __restrict__ meanb, const ushort* __restrict__ hb,
    const ushort* __restrict__ wb, const float* __restrict__ bias,
    const ushort* __restrict__ wbo, const float* __restrict__ bias_o,
    float* __restrict__ outp, int n) {
  __shared__ ushort smem[2 * 64 * 128];  // 32 KB: zA | zX, later reused as zo
  ushort* zA = smem;
  ushort* zX = smem + 64 * 128;
  float* zo = (float*)smem;  // 64*112 f32 = 28 KB
  const int t = threadIdx.x;
  const int block0 = blockIdx.x * 64;
#pragma unroll
  for (int i = 0; i < 4; ++i) {
    int c = i * 256 + t;
    int row = c >> 4;
    int col = c & 15;
    int node = block0 + row;
    int4 va = make_int4(0, 0, 0, 0), vx = make_int4(0, 0, 0, 0);
    if (node < n) {
      va = ((const int4*)(meanb + (size_t)node * 128))[col];
      vx = ((const int4*)(hb + (size_t)node * 128))[col];
    }
    ((int4*)zA)[c] = va;
    ((int4*)zX)[c] = vx;
  }
  __syncthreads();
  const int lane = t & 63;
  const int wave = t >> 6;
  const int m0 = wave * 16;
  const int cidx = lane & 15;
  const int quad = lane >> 4;
  f32x4 acc[8];
#pragma unroll
  for (int nt = 0; nt < 8; ++nt) acc[nt] = (f32x4){0.f, 0.f, 0.f, 0.f};
#pragma unroll
  for (int s = 0; s < 2; ++s) {
    const ushort* zs = (s == 0) ? zA : zX;
#pragma unroll
    for (int ks = 0; ks < 4; ++ks) {
      bf16x8 a = *(const bf16x8*)(zs + (m0 + cidx) * 128 + ks * 32 + quad * 8);
      const ushort* wp = wb + ((size_t)((s * 4 + ks) * 8) * 64 + lane) * 8;
#pragma unroll
      for (int nt = 0; nt < 8; ++nt) {
        bf16x8 b = *(const bf16x8*)(wp + nt * 512);
        acc[nt] = __builtin_amdgcn_mfma_f32_16x16x32_bf16(a, b, acc[nt], 0, 0, 0);
      }
    }
  }
  // h2 = relu(acc+bias) -> bf16 into zX OWN rows (A-reads above were own rows
  // only, so no cross-wave hazard; per-wave LDS ops are in-order).
#pragma unroll
  for (int nt = 0; nt < 8; ++nt) {
    float bv = bias[nt * 16 + cidx];
#pragma unroll
    for (int i = 0; i < 4; ++i) {
      float v = fmaxf(acc[nt][i] + bv, 0.f);
      zX[(m0 + quad * 4 + i) * 128 + nt * 16 + cidx] = f2b(v);
    }
  }
  // out projection from own h2 rows
  f32x4 acc2[7];
#pragma unroll
  for (int nt = 0; nt < 7; ++nt) acc2[nt] = (f32x4){0.f, 0.f, 0.f, 0.f};
#pragma unroll
  for (int ks = 0; ks < 4; ++ks) {
    bf16x8 a = *(const bf16x8*)(zX + (m0 + cidx) * 128 + ks * 32 + quad * 8);
    const ushort* wp = wbo + ((size_t)(ks * 7) * 64 + lane) * 8;
#pragma unroll
    for (int nt = 0; nt < 7; ++nt) {
      bf16x8 b = *(const bf16x8*)(wp + nt * 512);
      acc2[nt] = __builtin_amdgcn_mfma_f32_16x16x32_bf16(a, b, acc2[nt], 0, 0, 0);
    }
  }
  __syncthreads();  // all h2/zA reads done before zo overwrites smem
#pragma unroll
  for (int nt = 0; nt < 7; ++nt) {
    float bv = bias_o[nt * 16 + cidx];
#pragma unroll
    for (int i = 0; i < 4; ++i)
      zo[(m0 + quad * 4 + i) * 112 + nt * 16 + cidx] = acc2[nt][i] + bv;
  }
  __syncthreads();
  // 64x112 fp32 tile contiguous in outp -> coalesced float4 copy
#pragma unroll
  for (int i = 0; i < 7; ++i) {
    int c = i * 256 + t;
    int node = block0 + c / 28;  // 28 float4 per row
    if (node < n)
      ((float4*)(outp + (size_t)block0 * 112))[c] = ((const float4*)zo)[c];
  }
}

extern "C" void kernel_launch(void* const* d_in, const int* in_sizes, int n_in,
                              void* d_out, int out_size, void* d_ws, size_t ws_size,
                              hipStream_t stream) {
  const float* x     = (const float*)d_in[0];
  const int*   ei    = (const int*)d_in[1];
  const float* W_l1  = (const float*)d_in[2];
  const float* b_l1  = (const float*)d_in[3];
  const float* W_r1  = (const float*)d_in[4];
  const float* W_l2  = (const float*)d_in[5];
  const float* b_l2  = (const float*)d_in[6];
  const float* W_r2  = (const float*)d_in[7];
  const float* W_out = (const float*)d_in[8];
  const float* b_out = (const float*)d_in[9];

  const int N = in_sizes[0] / 128;
  const int E = in_sizes[1] / 2;
  const int NB = (N + 127) >> 7;
  const int* src = ei;
  const int* dst = ei + E;

  ushort* XB = (ushort*)d_ws;               // N*128 bf16 (x)
  ushort* MB = XB + (size_t)N * 128;        // N*128 bf16 (mean)
  ushort* HB = MB + (size_t)N * 128;        // N*128 bf16 (h1)
  float* DINV = (float*)(HB + (size_t)N * 128);  // N f32
  ushort* WB1 = (ushort*)(DINV + N);        // 32768
  ushort* WB2 = WB1 + 32768;                // 32768
  ushort* WBO = WB2 + 32768;                // 14336
  int* GCOUNT   = (int*)(WBO + 14336);      // NB
  int* GBASE    = GCOUNT + NB;              // NB+1
  int* GCURSOR  = GBASE + NB + 1;           // NB
  int* ROWSTART = GCURSOR + NB;             // N+1
  uint* BEDGES  = (uint*)(ROWSTART + N + 1);// E
  int* CSRSRC   = (int*)(BEDGES + E);       // E

  hipMemsetAsync(GCOUNT, 0, (size_t)NB * sizeof(int), stream);

  // ---- merged prep: f2b + hist + packw
  int n4 = N * 128 / 4;
  int f2b_blocks = (n4 + 255) / 256;
  int hist_blocks = (E + 4095) / 4096;
  int packw_blocks = 312;
  prep_kernel<<<f2b_blocks + hist_blocks + packw_blocks, 256, 0, stream>>>(
      x, XB, n4, dst, GCOUNT, E, NB,
      W_l1, W_r1, W_l2, W_r2, W_out, WB1, WB2, WBO,
      f2b_blocks, hist_blocks);

  // ---- CSR build
  scan_nb_kernel<<<1, 1024, 0, stream>>>(GCOUNT, GBASE, GCURSOR, ROWSTART, E, N, NB);
  bucket_scatter_kernel<<<(E + 8191) / 8192, 1024, 0, stream>>>(
      src, dst, GCURSOR, BEDGES, E, NB);
  csr_build_kernel<<<NB, 256, 0, stream>>>(BEDGES, GBASE, ROWSTART, DINV, CSRSRC, N);

  int ablocks = (N + 3) / 4;
  int lblocks = (N + 63) / 64;

  // layer 1
  agg_bf16_kernel<<<ablocks, 256, 0, stream>>>(XB, CSRSRC, ROWSTART, DINV, MB, N);
  lin_mfma_kernel<<<lblocks, 256, 0, stream>>>(MB, XB, WB1, b_l1, HB, N);

  // layer 2 + output projection (fused)
  agg_bf16_kernel<<<ablocks, 256, 0, stream>>>(HB, CSRSRC, ROWSTART, DINV, MB, N);
  lin2out_kernel<<<lblocks, 256, 0, stream>>>(MB, HB, WB2, b_l2, WBO, b_out,
                                              (float*)d_out, N);
}